// Round 1
// baseline (642.143 us; speedup 1.0000x reference)
//
#include <hip/hip_runtime.h>
#include <math.h>

#define NEG_SLOPE 0.2f

__device__ __forceinline__ float lrelu(float x){ return x > 0.f ? x : NEG_SLOPE * x; }

// ---------------- CSR build ----------------
__global__ void k_count(const int* __restrict__ dst, int* __restrict__ deg, int E){
  int e = blockIdx.x*256 + threadIdx.x;
  if (e < E) atomicAdd(&deg[dst[e]], 1);
}

__global__ void k_scan(const int* __restrict__ deg, int* __restrict__ rowptr,
                       int* __restrict__ nxt, int n){
  __shared__ int wsum[16];
  __shared__ int s_carry;
  int tid = threadIdx.x;
  int lane = tid & 63, wid = tid >> 6;
  if (tid == 0) s_carry = 0;
  __syncthreads();
  for (int base = 0; base < n; base += 1024){
    int i = base + tid;
    int v = (i < n) ? deg[i] : 0;
    int inc = v;
    #pragma unroll
    for (int off=1; off<64; off<<=1){ int t = __shfl_up(inc, off); if (lane >= off) inc += t; }
    if (lane == 63) wsum[wid] = inc;
    __syncthreads();
    int carry = s_carry;
    if (wid == 0 && lane < 16){
      int wv = wsum[lane];
      #pragma unroll
      for (int off=1; off<16; off<<=1){ int t = __shfl_up(wv, off); if (lane >= off) wv += t; }
      wsum[lane] = wv;
    }
    __syncthreads();
    int woff = (wid == 0) ? 0 : wsum[wid-1];
    int excl = carry + woff + inc - v;
    if (i < n){ rowptr[i] = excl; nxt[i] = excl; }
    __syncthreads();
    if (tid == 0) s_carry = carry + wsum[15];
    __syncthreads();
  }
  if (tid == 0) rowptr[n] = s_carry;
}

__global__ void k_scatter(const int* __restrict__ src, const int* __restrict__ dst,
                          int* __restrict__ nxt, int* __restrict__ srcs, int E){
  int e = blockIdx.x*256 + threadIdx.x;
  if (e < E){
    int pos = atomicAdd(&nxt[dst[e]], 1);
    srcs[pos] = src[e];
  }
}

// ---------------- generic fp32 GEMM: C[M,NC] = A[M,K] @ B[K,NC] ----------------
// 64x64 tile, K-step 32, 256 threads, thread computes 4x4.
__global__ __launch_bounds__(256) void gemm64(
    const float* __restrict__ A, const float* __restrict__ B, float* __restrict__ C,
    int M, int K, int NC){
  __shared__ __align__(16) float xs[64][36];
  __shared__ __align__(16) float wb[32][64];
  const int tid = threadIdx.x;
  const int r0 = blockIdx.x * 64;
  const int c0 = blockIdx.y * 64;
  const int tr = tid >> 4, tc = tid & 15;
  const int K4 = K >> 2, NC4 = NC >> 2;
  float acc[4][4];
  #pragma unroll
  for (int i=0;i<4;i++)
    #pragma unroll
    for (int j=0;j<4;j++) acc[i][j] = 0.f;

  for (int k0 = 0; k0 < K; k0 += 32){
    #pragma unroll
    for (int t=0; t<2; t++){
      int id = tid + t*256;          // 0..511
      int r = id >> 3, kq = id & 7;
      float4 v = make_float4(0.f,0.f,0.f,0.f);
      int row = r0 + r;
      if (row < M) v = ((const float4*)A)[(size_t)row*K4 + (k0>>2) + kq];
      *((float4*)&xs[r][kq*4]) = v;
    }
    #pragma unroll
    for (int t=0; t<2; t++){
      int id = tid + t*256;
      int kk = id >> 4, cq = id & 15;
      float4 v = make_float4(0.f,0.f,0.f,0.f);
      int c = c0 + cq*4;
      if (c < NC) v = ((const float4*)B)[(size_t)(k0+kk)*NC4 + (c>>2)];
      *((float4*)&wb[kk][cq*4]) = v;
    }
    __syncthreads();
    #pragma unroll
    for (int kk=0; kk<32; kk+=4){
      float4 a0 = *((const float4*)&xs[tr*4+0][kk]);
      float4 a1 = *((const float4*)&xs[tr*4+1][kk]);
      float4 a2 = *((const float4*)&xs[tr*4+2][kk]);
      float4 a3 = *((const float4*)&xs[tr*4+3][kk]);
      float4 b0 = *((const float4*)&wb[kk+0][tc*4]);
      float4 b1 = *((const float4*)&wb[kk+1][tc*4]);
      float4 b2 = *((const float4*)&wb[kk+2][tc*4]);
      float4 b3 = *((const float4*)&wb[kk+3][tc*4]);
      #define FMA_ROW(ai, i) \
        acc[i][0] += ai.x*b0.x + ai.y*b1.x + ai.z*b2.x + ai.w*b3.x; \
        acc[i][1] += ai.x*b0.y + ai.y*b1.y + ai.z*b2.y + ai.w*b3.y; \
        acc[i][2] += ai.x*b0.z + ai.y*b1.z + ai.z*b2.z + ai.w*b3.z; \
        acc[i][3] += ai.x*b0.w + ai.y*b1.w + ai.z*b2.w + ai.w*b3.w;
      FMA_ROW(a0, 0) FMA_ROW(a1, 1) FMA_ROW(a2, 2) FMA_ROW(a3, 3)
      #undef FMA_ROW
    }
    __syncthreads();
  }
  #pragma unroll
  for (int i=0;i<4;i++){
    int row = r0 + tr*4 + i;
    int c = c0 + tc*4;
    if (row < M && c < NC){
      float4 o = make_float4(acc[i][0], acc[i][1], acc[i][2], acc[i][3]);
      ((float4*)C)[(size_t)row*NC4 + (c>>2)] = o;
    }
  }
}

// ---------------- attention coefficient dots ----------------
__global__ void k_att1(const float* __restrict__ h, const float* __restrict__ att_s,
    const float* __restrict__ att_d, float* __restrict__ asrc, float* __restrict__ adst, int n){
  int id = blockIdx.x*256 + threadIdx.x;   // id = node*8 + head
  if (id >= n*8) return;
  int hd = id & 7;
  const float4* hv = (const float4*)(h + (size_t)(id>>3)*256 + hd*32);
  const float4* s4 = (const float4*)(att_s + hd*32);
  const float4* d4 = (const float4*)(att_d + hd*32);
  float s = 0.f, d = 0.f;
  #pragma unroll
  for (int q=0; q<8; q++){
    float4 v = hv[q], a = s4[q], b = d4[q];
    s += v.x*a.x + v.y*a.y + v.z*a.z + v.w*a.w;
    d += v.x*b.x + v.y*b.y + v.z*b.z + v.w*b.w;
  }
  asrc[id] = s; adst[id] = d;
}

__global__ void k_att2(const float* __restrict__ h, const float* __restrict__ att_s,
    const float* __restrict__ att_d, float* __restrict__ asrc, float* __restrict__ adst, int n){
  int id = blockIdx.x*256 + threadIdx.x;   // id = node
  if (id >= n) return;
  const float4* hv = (const float4*)(h + (size_t)id*40);
  const float4* s4 = (const float4*)att_s;
  const float4* d4 = (const float4*)att_d;
  float s = 0.f, d = 0.f;
  #pragma unroll
  for (int q=0; q<10; q++){
    float4 v = hv[q], a = s4[q], b = d4[q];
    s += v.x*a.x + v.y*a.y + v.z*a.z + v.w*a.w;
    d += v.x*b.x + v.y*b.y + v.z*b.z + v.w*b.w;
  }
  asrc[id] = s; adst[id] = d;
}

// ---------------- layer-1 aggregation: wave per node, 256 channels ----------------
__global__ __launch_bounds__(256) void k_agg1(
    const float* __restrict__ h1, const float* __restrict__ asrc,
    const float* __restrict__ adst, const int* __restrict__ rowptr,
    const int* __restrict__ srcs, const float* __restrict__ bias,
    float* __restrict__ z, int n){
  int wid = (blockIdx.x*256 + threadIdx.x) >> 6;
  int lane = threadIdx.x & 63;
  if (wid >= n) return;
  int i = wid;
  int hd = lane >> 3;                      // channels lane*4..+3 all in head lane/8
  float adsti = adst[(size_t)i*8 + hd];
  float selfl = lrelu(asrc[(size_t)i*8 + hd] + adsti);
  int e0 = rowptr[i], e1 = rowptr[i+1];
  float m = selfl;
  for (int e = e0; e < e1; ++e){
    int s = srcs[e];
    m = fmaxf(m, lrelu(asrc[(size_t)s*8 + hd] + adsti));
  }
  float pself = __expf(selfl - m);
  float ssum = pself;
  float4 hv = ((const float4*)(h1 + (size_t)i*256))[lane];
  float4 acc = make_float4(hv.x*pself, hv.y*pself, hv.z*pself, hv.w*pself);
  for (int e = e0; e < e1; ++e){
    int s = srcs[e];
    float p = __expf(lrelu(asrc[(size_t)s*8 + hd] + adsti) - m);
    ssum += p;
    float4 v = ((const float4*)(h1 + (size_t)s*256))[lane];
    acc.x += p*v.x; acc.y += p*v.y; acc.z += p*v.z; acc.w += p*v.w;
  }
  float inv = 1.f / ssum;
  float4 b = ((const float4*)bias)[lane];
  float4 o;
  o.x = fmaxf(fmaf(acc.x, inv, b.x), 0.f);
  o.y = fmaxf(fmaf(acc.y, inv, b.y), 0.f);
  o.z = fmaxf(fmaf(acc.z, inv, b.z), 0.f);
  o.w = fmaxf(fmaf(acc.w, inv, b.w), 0.f);
  ((float4*)(z + (size_t)i*256))[lane] = o;
}

// ---------------- layer-2 aggregation + log_softmax: wave per node, 40 channels ----------------
__global__ __launch_bounds__(256) void k_agg2(
    const float* __restrict__ h2, const float* __restrict__ asrc,
    const float* __restrict__ adst, const int* __restrict__ rowptr,
    const int* __restrict__ srcs, const float* __restrict__ bias,
    float* __restrict__ out, int n){
  int wid = (blockIdx.x*256 + threadIdx.x) >> 6;
  int lane = threadIdx.x & 63;
  if (wid >= n) return;
  int i = wid;
  bool act = lane < 40;
  float adsti = adst[i];
  float selfl = lrelu(asrc[i] + adsti);
  int e0 = rowptr[i], e1 = rowptr[i+1];
  float m = selfl;
  for (int e = e0; e < e1; ++e){
    m = fmaxf(m, lrelu(asrc[srcs[e]] + adsti));
  }
  float pself = __expf(selfl - m);
  float ssum = pself;
  float acc = act ? h2[(size_t)i*40 + lane] * pself : 0.f;
  for (int e = e0; e < e1; ++e){
    int s = srcs[e];
    float p = __expf(lrelu(asrc[s] + adsti) - m);
    ssum += p;
    if (act) acc += p * h2[(size_t)s*40 + lane];
  }
  float val = act ? (acc / ssum + bias[lane]) : -INFINITY;
  // log_softmax over 40 classes (lanes >= 40 hold neutral values)
  float mx = val;
  #pragma unroll
  for (int off=32; off; off>>=1) mx = fmaxf(mx, __shfl_xor(mx, off));
  float ex = act ? __expf(val - mx) : 0.f;
  float se = ex;
  #pragma unroll
  for (int off=32; off; off>>=1) se += __shfl_xor(se, off);
  if (act) out[(size_t)i*40 + lane] = val - mx - __logf(se);
}

extern "C" void kernel_launch(void* const* d_in, const int* in_sizes, int n_in,
                              void* d_out, int out_size, void* d_ws, size_t ws_size,
                              hipStream_t stream){
  const float* x   = (const float*)d_in[0];
  const int*   ei  = (const int*)d_in[1];
  const float* W1  = (const float*)d_in[2];
  const float* as1 = (const float*)d_in[3];
  const float* ad1 = (const float*)d_in[4];
  const float* b1  = (const float*)d_in[5];
  const float* W2  = (const float*)d_in[6];
  const float* as2 = (const float*)d_in[7];
  const float* ad2 = (const float*)d_in[8];
  const float* b2  = (const float*)d_in[9];
  float* out = (float*)d_out;

  const int N = in_sizes[0] / 128;
  const int E = in_sizes[1] / 2;
  const int* srcI = ei;
  const int* dstI = ei + E;

  char* ws = (char*)d_ws;
  size_t off = 0;
  auto alloc = [&](size_t bytes){ void* p = ws + off; off += (bytes + 255) & ~(size_t)255; return p; };
  float* h1    = (float*)alloc((size_t)N*256*4);
  float* z     = (float*)alloc((size_t)N*256*4);
  float* h2    = (float*)alloc((size_t)N*40*4);
  float* asrc1 = (float*)alloc((size_t)N*8*4);
  float* adst1 = (float*)alloc((size_t)N*8*4);
  float* asrc2 = (float*)alloc((size_t)N*4);
  float* adst2 = (float*)alloc((size_t)N*4);
  int* deg     = (int*)alloc((size_t)N*4);
  int* rowptr  = (int*)alloc((size_t)(N+1)*4);
  int* nxt     = (int*)alloc((size_t)N*4);
  int* srcs    = (int*)alloc((size_t)E*4);
  (void)ws_size; (void)n_in; (void)out_size;

  hipMemsetAsync(deg, 0, (size_t)N*4, stream);
  int eb = (E + 255)/256;
  k_count  <<<eb, 256, 0, stream>>>(dstI, deg, E);
  k_scan   <<<1, 1024, 0, stream>>>(deg, rowptr, nxt, N);
  k_scatter<<<eb, 256, 0, stream>>>(srcI, dstI, nxt, srcs, E);

  dim3 g1((N + 63)/64, 4);
  gemm64<<<g1, 256, 0, stream>>>(x, W1, h1, N, 128, 256);
  k_att1<<<(N*8 + 255)/256, 256, 0, stream>>>(h1, as1, ad1, asrc1, adst1, N);
  k_agg1<<<(N + 3)/4, 256, 0, stream>>>(h1, asrc1, adst1, rowptr, srcs, b1, z, N);

  dim3 g2((N + 63)/64, 1);
  gemm64<<<g2, 256, 0, stream>>>(z, W2, h2, N, 256, 40);
  k_att2<<<(N + 255)/256, 256, 0, stream>>>(h2, as2, ad2, asrc2, adst2, N);
  k_agg2<<<(N + 3)/4, 256, 0, stream>>>(h2, asrc2, adst2, rowptr, srcs, b2, out, N);
}

// Round 2
// 408.949 us; speedup vs baseline: 1.5702x; 1.5702x over previous
//
#include <hip/hip_runtime.h>
#include <hip/hip_bf16.h>
#include <math.h>

#define NEG_SLOPE 0.2f

__device__ __forceinline__ float lrelu(float x){ return x > 0.f ? x : NEG_SLOPE * x; }
__device__ __forceinline__ unsigned short f2bf(float f){
  __hip_bfloat16 h = __float2bfloat16(f);
  return __builtin_bit_cast(unsigned short, h);
}

typedef short bf16x8 __attribute__((ext_vector_type(8)));
typedef float f32x4 __attribute__((ext_vector_type(4)));

// ---------------- CSR build ----------------
__global__ void k_count(const int* __restrict__ dst, int* __restrict__ deg, int E){
  int e = blockIdx.x*256 + threadIdx.x;
  if (e < E) atomicAdd(&deg[dst[e]], 1);
}

// phase 1: per-block (1024-chunk) sums
__global__ __launch_bounds__(256) void k_scan1(const int* __restrict__ deg, int* __restrict__ bsum, int n){
  int tid = threadIdx.x;
  int base = blockIdx.x*1024 + tid*4;
  int s = 0;
  #pragma unroll
  for (int j=0;j<4;j++){ int idx = base+j; if (idx < n) s += deg[idx]; }
  #pragma unroll
  for (int off=32; off; off>>=1) s += __shfl_xor(s, off);
  __shared__ int ws[4];
  if ((tid&63)==0) ws[tid>>6] = s;
  __syncthreads();
  if (tid==0) bsum[blockIdx.x] = ws[0]+ws[1]+ws[2]+ws[3];
}

// phase 2: exclusive scan of block sums (nb <= 64), one wave
__global__ void k_scan2(const int* __restrict__ bsum, int* __restrict__ boff,
                        int* __restrict__ rowptr, int nb, int n){
  int lane = threadIdx.x;
  int v = (lane < nb) ? bsum[lane] : 0;
  int inc = v;
  #pragma unroll
  for (int off=1; off<64; off<<=1){ int t = __shfl_up(inc, off); if (lane >= off) inc += t; }
  if (lane < nb) boff[lane] = inc - v;
  if (lane == 63) rowptr[n] = inc;
}

// phase 3: local scan + block offset -> rowptr, nxt
__global__ __launch_bounds__(256) void k_scan3(const int* __restrict__ deg, const int* __restrict__ boff,
    int* __restrict__ rowptr, int* __restrict__ nxt, int n){
  int tid = threadIdx.x; int lane = tid & 63, w = tid >> 6;
  int base = blockIdx.x*1024 + tid*4;
  int v[4]; int s = 0;
  #pragma unroll
  for (int j=0;j<4;j++){ int idx = base+j; v[j] = (idx < n) ? deg[idx] : 0; s += v[j]; }
  int inc = s;
  #pragma unroll
  for (int off=1; off<64; off<<=1){ int t = __shfl_up(inc, off); if (lane >= off) inc += t; }
  __shared__ int ws[4];
  if (lane == 63) ws[w] = inc;
  __syncthreads();
  int run = boff[blockIdx.x];
  for (int ww=0; ww<w; ww++) run += ws[ww];
  run += inc - s;
  #pragma unroll
  for (int j=0;j<4;j++){ int idx = base+j; if (idx < n){ rowptr[idx] = run; nxt[idx] = run; run += v[j]; } }
}

__global__ void k_scatter(const int* __restrict__ src, const int* __restrict__ dst,
                          int* __restrict__ nxt, int* __restrict__ srcs, int E){
  int e = blockIdx.x*256 + threadIdx.x;
  if (e < E){
    int pos = atomicAdd(&nxt[dst[e]], 1);
    srcs[pos] = src[e];
  }
}

// ---------------- conversions ----------------
__global__ void k_f2b(const float* __restrict__ a, unsigned short* __restrict__ b, int n4){
  int id = blockIdx.x*256 + threadIdx.x;
  if (id < n4){
    float4 v = ((const float4*)a)[id];
    ushort4 o; o.x = f2bf(v.x); o.y = f2bf(v.y); o.z = f2bf(v.z); o.w = f2bf(v.w);
    ((ushort4*)b)[id] = o;
  }
}

// Wt[c][k] = W[k][c] (bf16), c >= NCreal -> 0.  grid = NCpad blocks, block = K threads
__global__ void k_wt(const float* __restrict__ W, unsigned short* __restrict__ Wt, int NCreal){
  int c = blockIdx.x, k = threadIdx.x, K = blockDim.x;
  float v = (c < NCreal) ? W[(size_t)k*NCreal + c] : 0.f;
  Wt[(size_t)c*K + k] = f2bf(v);
}

// ---------------- bf16 MFMA GEMM: C[M][ldc](f32) = A[M][K](bf16) @ Bt[NB][K](bf16)^T ----
// 64x64 tile, 4 waves in 2x2, each wave 32x32 via 2x2 16x16x32 fragments.
__global__ __launch_bounds__(256) void gemm_mfma(
    const unsigned short* __restrict__ A, const unsigned short* __restrict__ Bt,
    float* __restrict__ C, int M, int K, int ldc){
  __shared__ unsigned short sA[64][40];
  __shared__ unsigned short sB[64][40];
  const int tid = threadIdx.x;
  const int wid = tid >> 6, lane = tid & 63;
  const int r0 = blockIdx.x * 64, c0 = blockIdx.y * 64;
  const int wr = wid >> 1, wc = wid & 1;
  const int lr = tid >> 2;           // staging row 0..63
  const int lk = (tid & 3) * 8;      // staging k-offset
  const int fr = lane & 15, fk = (lane >> 4) * 8;
  f32x4 acc[2][2] = {};

  for (int k0 = 0; k0 < K; k0 += 32){
    uint4 va = make_uint4(0,0,0,0);
    int row = r0 + lr;
    if (row < M) va = *(const uint4*)(A + (size_t)row*K + k0 + lk);
    *(uint4*)&sA[lr][lk] = va;
    uint4 vb = *(const uint4*)(Bt + (size_t)(c0 + lr)*K + k0 + lk);
    *(uint4*)&sB[lr][lk] = vb;
    __syncthreads();
    bf16x8 a0 = *(const bf16x8*)&sA[wr*32 + fr][fk];
    bf16x8 a1 = *(const bf16x8*)&sA[wr*32 + 16 + fr][fk];
    bf16x8 b0 = *(const bf16x8*)&sB[wc*32 + fr][fk];
    bf16x8 b1 = *(const bf16x8*)&sB[wc*32 + 16 + fr][fk];
    acc[0][0] = __builtin_amdgcn_mfma_f32_16x16x32_bf16(a0, b0, acc[0][0], 0,0,0);
    acc[0][1] = __builtin_amdgcn_mfma_f32_16x16x32_bf16(a0, b1, acc[0][1], 0,0,0);
    acc[1][0] = __builtin_amdgcn_mfma_f32_16x16x32_bf16(a1, b0, acc[1][0], 0,0,0);
    acc[1][1] = __builtin_amdgcn_mfma_f32_16x16x32_bf16(a1, b1, acc[1][1], 0,0,0);
    __syncthreads();
  }
  #pragma unroll
  for (int mi=0; mi<2; mi++){
    int rowb = r0 + wr*32 + mi*16 + (lane>>4)*4;
    #pragma unroll
    for (int ni=0; ni<2; ni++){
      int col = c0 + wc*32 + ni*16 + fr;
      #pragma unroll
      for (int j=0;j<4;j++){
        int row = rowb + j;
        if (row < M) C[(size_t)row*ldc + col] = acc[mi][ni][j];
      }
    }
  }
}

// ---------------- attention coefficient dots ----------------
__global__ void k_att1(const float* __restrict__ h, const float* __restrict__ att_s,
    const float* __restrict__ att_d, float* __restrict__ asrc, float* __restrict__ adst, int n){
  int id = blockIdx.x*256 + threadIdx.x;   // id = node*8 + head
  if (id >= n*8) return;
  int hd = id & 7;
  const float4* hv = (const float4*)(h + (size_t)(id>>3)*256 + hd*32);
  const float4* s4 = (const float4*)(att_s + hd*32);
  const float4* d4 = (const float4*)(att_d + hd*32);
  float s = 0.f, d = 0.f;
  #pragma unroll
  for (int q=0; q<8; q++){
    float4 v = hv[q], a = s4[q], b = d4[q];
    s += v.x*a.x + v.y*a.y + v.z*a.z + v.w*a.w;
    d += v.x*b.x + v.y*b.y + v.z*b.z + v.w*b.w;
  }
  asrc[id] = s; adst[id] = d;
}

__global__ void k_att2(const float* __restrict__ h, const float* __restrict__ att_s,
    const float* __restrict__ att_d, float* __restrict__ asrc, float* __restrict__ adst, int n){
  int id = blockIdx.x*256 + threadIdx.x;   // id = node
  if (id >= n) return;
  const float4* hv = (const float4*)(h + (size_t)id*64);
  const float4* s4 = (const float4*)att_s;
  const float4* d4 = (const float4*)att_d;
  float s = 0.f, d = 0.f;
  #pragma unroll
  for (int q=0; q<10; q++){
    float4 v = hv[q], a = s4[q], b = d4[q];
    s += v.x*a.x + v.y*a.y + v.z*a.z + v.w*a.w;
    d += v.x*b.x + v.y*b.y + v.z*b.z + v.w*b.w;
  }
  asrc[id] = s; adst[id] = d;
}

// ---------------- layer-1 aggregation: wave/node, online softmax, 4x unrolled ------
__global__ __launch_bounds__(256) void k_agg1(
    const float* __restrict__ h1, const float* __restrict__ asrc,
    const float* __restrict__ adst, const int* __restrict__ rowptr,
    const int* __restrict__ srcs, const float* __restrict__ bias,
    unsigned short* __restrict__ zb, int n){
  int wid = (blockIdx.x*256 + threadIdx.x) >> 6;
  int lane = threadIdx.x & 63;
  if (wid >= n) return;
  int i = wid;
  int hd = lane >> 3;
  float adsti = adst[(size_t)i*8 + hd];
  float m = lrelu(asrc[(size_t)i*8 + hd] + adsti);   // self logit; p_self = 1
  float ssum = 1.f;
  float4 acc = ((const float4*)(h1 + (size_t)i*256))[lane];
  int e0 = rowptr[i], e1 = rowptr[i+1];
  int e = e0;
  for (; e + 4 <= e1; e += 4){
    int s0 = srcs[e], s1 = srcs[e+1], s2 = srcs[e+2], s3 = srcs[e+3];
    float4 v0 = ((const float4*)(h1 + (size_t)s0*256))[lane];
    float4 v1 = ((const float4*)(h1 + (size_t)s1*256))[lane];
    float4 v2 = ((const float4*)(h1 + (size_t)s2*256))[lane];
    float4 v3 = ((const float4*)(h1 + (size_t)s3*256))[lane];
    float l0 = lrelu(asrc[(size_t)s0*8 + hd] + adsti);
    float l1 = lrelu(asrc[(size_t)s1*8 + hd] + adsti);
    float l2 = lrelu(asrc[(size_t)s2*8 + hd] + adsti);
    float l3 = lrelu(asrc[(size_t)s3*8 + hd] + adsti);
    float gm = fmaxf(fmaxf(l0,l1), fmaxf(l2,l3));
    float mn = fmaxf(m, gm);
    float r = __expf(m - mn); m = mn;
    float p0 = __expf(l0 - m), p1 = __expf(l1 - m), p2 = __expf(l2 - m), p3 = __expf(l3 - m);
    ssum = ssum*r + p0 + p1 + p2 + p3;
    acc.x = acc.x*r + p0*v0.x + p1*v1.x + p2*v2.x + p3*v3.x;
    acc.y = acc.y*r + p0*v0.y + p1*v1.y + p2*v2.y + p3*v3.y;
    acc.z = acc.z*r + p0*v0.z + p1*v1.z + p2*v2.z + p3*v3.z;
    acc.w = acc.w*r + p0*v0.w + p1*v1.w + p2*v2.w + p3*v3.w;
  }
  for (; e < e1; ++e){
    int s = srcs[e];
    float4 v = ((const float4*)(h1 + (size_t)s*256))[lane];
    float l = lrelu(asrc[(size_t)s*8 + hd] + adsti);
    float mn = fmaxf(m, l);
    float r = __expf(m - mn);
    float p = __expf(l - mn); m = mn;
    ssum = ssum*r + p;
    acc.x = acc.x*r + p*v.x; acc.y = acc.y*r + p*v.y;
    acc.z = acc.z*r + p*v.z; acc.w = acc.w*r + p*v.w;
  }
  float inv = 1.f / ssum;
  float4 b = ((const float4*)bias)[lane];
  ushort4 ob;
  ob.x = f2bf(fmaxf(fmaf(acc.x, inv, b.x), 0.f));
  ob.y = f2bf(fmaxf(fmaf(acc.y, inv, b.y), 0.f));
  ob.z = f2bf(fmaxf(fmaf(acc.z, inv, b.z), 0.f));
  ob.w = f2bf(fmaxf(fmaf(acc.w, inv, b.w), 0.f));
  ((ushort4*)(zb + (size_t)i*256))[lane] = ob;
}

// ---------------- layer-2 aggregation + log_softmax ----------------
__global__ __launch_bounds__(256) void k_agg2(
    const float* __restrict__ h2, const float* __restrict__ asrc,
    const float* __restrict__ adst, const int* __restrict__ rowptr,
    const int* __restrict__ srcs, const float* __restrict__ bias,
    float* __restrict__ out, int n){
  int wid = (blockIdx.x*256 + threadIdx.x) >> 6;
  int lane = threadIdx.x & 63;
  if (wid >= n) return;
  int i = wid;
  bool act = lane < 40;
  float adsti = adst[i];
  float m = lrelu(asrc[i] + adsti);
  float ssum = 1.f;
  float acc = h2[(size_t)i*64 + lane];   // cols 40..63 are zeros
  int e0 = rowptr[i], e1 = rowptr[i+1];
  int e = e0;
  for (; e + 4 <= e1; e += 4){
    int s0 = srcs[e], s1 = srcs[e+1], s2 = srcs[e+2], s3 = srcs[e+3];
    float v0 = h2[(size_t)s0*64 + lane];
    float v1 = h2[(size_t)s1*64 + lane];
    float v2 = h2[(size_t)s2*64 + lane];
    float v3 = h2[(size_t)s3*64 + lane];
    float l0 = lrelu(asrc[s0] + adsti);
    float l1 = lrelu(asrc[s1] + adsti);
    float l2 = lrelu(asrc[s2] + adsti);
    float l3 = lrelu(asrc[s3] + adsti);
    float gm = fmaxf(fmaxf(l0,l1), fmaxf(l2,l3));
    float mn = fmaxf(m, gm);
    float r = __expf(m - mn); m = mn;
    float p0 = __expf(l0 - m), p1 = __expf(l1 - m), p2 = __expf(l2 - m), p3 = __expf(l3 - m);
    ssum = ssum*r + p0 + p1 + p2 + p3;
    acc  = acc*r + p0*v0 + p1*v1 + p2*v2 + p3*v3;
  }
  for (; e < e1; ++e){
    int s = srcs[e];
    float v = h2[(size_t)s*64 + lane];
    float l = lrelu(asrc[s] + adsti);
    float mn = fmaxf(m, l);
    float r = __expf(m - mn);
    float p = __expf(l - mn); m = mn;
    ssum = ssum*r + p;
    acc  = acc*r + p*v;
  }
  float val = act ? (acc/ssum + bias[lane]) : -INFINITY;
  float mx = val;
  #pragma unroll
  for (int off=32; off; off>>=1) mx = fmaxf(mx, __shfl_xor(mx, off));
  float ex = act ? __expf(val - mx) : 0.f;
  float se = ex;
  #pragma unroll
  for (int off=32; off; off>>=1) se += __shfl_xor(se, off);
  if (act) out[(size_t)i*40 + lane] = val - mx - __logf(se);
}

extern "C" void kernel_launch(void* const* d_in, const int* in_sizes, int n_in,
                              void* d_out, int out_size, void* d_ws, size_t ws_size,
                              hipStream_t stream){
  const float* x   = (const float*)d_in[0];
  const int*   ei  = (const int*)d_in[1];
  const float* W1  = (const float*)d_in[2];
  const float* as1 = (const float*)d_in[3];
  const float* ad1 = (const float*)d_in[4];
  const float* b1  = (const float*)d_in[5];
  const float* W2  = (const float*)d_in[6];
  const float* as2 = (const float*)d_in[7];
  const float* ad2 = (const float*)d_in[8];
  const float* b2  = (const float*)d_in[9];
  float* out = (float*)d_out;

  const int N = in_sizes[0] / 128;
  const int E = in_sizes[1] / 2;
  const int* srcI = ei;
  const int* dstI = ei + E;

  char* ws = (char*)d_ws;
  size_t off = 0;
  auto alloc = [&](size_t bytes){ void* p = ws + off; off += (bytes + 255) & ~(size_t)255; return p; };
  float*  h1   = (float*)alloc((size_t)N*256*4);
  unsigned short* xb  = (unsigned short*)alloc((size_t)N*128*2);
  unsigned short* zb  = (unsigned short*)alloc((size_t)N*256*2);
  float*  h2   = (float*)alloc((size_t)N*64*4);
  unsigned short* W1t = (unsigned short*)alloc((size_t)256*128*2);
  unsigned short* W2t = (unsigned short*)alloc((size_t)64*256*2);
  float* asrc1 = (float*)alloc((size_t)N*8*4);
  float* adst1 = (float*)alloc((size_t)N*8*4);
  float* asrc2 = (float*)alloc((size_t)N*4);
  float* adst2 = (float*)alloc((size_t)N*4);
  int* deg     = (int*)alloc((size_t)N*4);
  int* rowptr  = (int*)alloc((size_t)(N+1)*4);
  int* nxt     = (int*)alloc((size_t)N*4);
  int* srcs    = (int*)alloc((size_t)E*4);
  int* bsum    = (int*)alloc(256*4);
  int* boff    = (int*)alloc(256*4);
  (void)ws_size; (void)n_in; (void)out_size;

  const int nb = (N + 1023)/1024;
  hipMemsetAsync(deg, 0, (size_t)N*4, stream);
  int eb = (E + 255)/256;
  k_count <<<eb, 256, 0, stream>>>(dstI, deg, E);
  k_scan1 <<<nb, 256, 0, stream>>>(deg, bsum, N);
  k_scan2 <<<1, 64, 0, stream>>>(bsum, boff, rowptr, nb, N);
  k_scan3 <<<nb, 256, 0, stream>>>(deg, boff, rowptr, nxt, N);
  k_scatter<<<eb, 256, 0, stream>>>(srcI, dstI, nxt, srcs, E);

  // conversions
  k_f2b<<<((N*128/4) + 255)/256, 256, 0, stream>>>(x, xb, N*128/4);
  k_wt <<<256, 128, 0, stream>>>(W1, W1t, 256);
  k_wt <<<64, 256, 0, stream>>>(W2, W2t, 40);

  // layer 1
  dim3 g1((N + 63)/64, 4);
  gemm_mfma<<<g1, 256, 0, stream>>>(xb, W1t, h1, N, 128, 256);
  k_att1<<<(N*8 + 255)/256, 256, 0, stream>>>(h1, as1, ad1, asrc1, adst1, N);
  k_agg1<<<(N + 3)/4, 256, 0, stream>>>(h1, asrc1, adst1, rowptr, srcs, b1, zb, N);

  // layer 2
  dim3 g2((N + 63)/64, 1);
  gemm_mfma<<<g2, 256, 0, stream>>>(zb, W2t, h2, N, 256, 64);
  k_att2<<<(N + 255)/256, 256, 0, stream>>>(h2, as2, ad2, asrc2, adst2, N);
  k_agg2<<<(N + 3)/4, 256, 0, stream>>>(h2, asrc2, adst2, rowptr, srcs, b2, out, N);
}

// Round 4
// 340.162 us; speedup vs baseline: 1.8878x; 1.2022x over previous
//
#include <hip/hip_runtime.h>
#include <hip/hip_bf16.h>
#include <math.h>

#define NEG_SLOPE 0.2f

__device__ __forceinline__ float lrelu(float x){ return x > 0.f ? x : NEG_SLOPE * x; }
__device__ __forceinline__ unsigned short f2bf(float f){
  __hip_bfloat16 h = __float2bfloat16(f);
  return __builtin_bit_cast(unsigned short, h);
}
__device__ __forceinline__ float b2f(unsigned short u){
  return __builtin_bit_cast(float, (unsigned)u << 16);
}

typedef short bf16x8 __attribute__((ext_vector_type(8)));
typedef float f32x4 __attribute__((ext_vector_type(4)));

// ---------------- CSR build ----------------
__global__ void k_count(const int* __restrict__ dst, int* __restrict__ deg, int E){
  int e = blockIdx.x*256 + threadIdx.x;
  if (e < E) atomicAdd(&deg[dst[e]], 1);
}

__global__ __launch_bounds__(256) void k_scan1(const int* __restrict__ deg, int* __restrict__ bsum, int n){
  int tid = threadIdx.x;
  int base = blockIdx.x*1024 + tid*4;
  int s = 0;
  #pragma unroll
  for (int j=0;j<4;j++){ int idx = base+j; if (idx < n) s += deg[idx]; }
  #pragma unroll
  for (int off=32; off; off>>=1) s += __shfl_xor(s, off);
  __shared__ int ws[4];
  if ((tid&63)==0) ws[tid>>6] = s;
  __syncthreads();
  if (tid==0) bsum[blockIdx.x] = ws[0]+ws[1]+ws[2]+ws[3];
}

__global__ void k_scan2(const int* __restrict__ bsum, int* __restrict__ boff,
                        int* __restrict__ rowptr, int nb, int n){
  int lane = threadIdx.x;
  int v = (lane < nb) ? bsum[lane] : 0;
  int inc = v;
  #pragma unroll
  for (int off=1; off<64; off<<=1){ int t = __shfl_up(inc, off); if (lane >= off) inc += t; }
  if (lane < nb) boff[lane] = inc - v;
  if (lane == 63) rowptr[n] = inc;
}

__global__ __launch_bounds__(256) void k_scan3(const int* __restrict__ deg, const int* __restrict__ boff,
    int* __restrict__ rowptr, int* __restrict__ nxt, int n){
  int tid = threadIdx.x; int lane = tid & 63, w = tid >> 6;
  int base = blockIdx.x*1024 + tid*4;
  int v[4]; int s = 0;
  #pragma unroll
  for (int j=0;j<4;j++){ int idx = base+j; v[j] = (idx < n) ? deg[idx] : 0; s += v[j]; }
  int inc = s;
  #pragma unroll
  for (int off=1; off<64; off<<=1){ int t = __shfl_up(inc, off); if (lane >= off) inc += t; }
  __shared__ int ws[4];
  if (lane == 63) ws[w] = inc;
  __syncthreads();
  int run = boff[blockIdx.x];
  for (int ww=0; ww<w; ww++) run += ws[ww];
  run += inc - s;
  #pragma unroll
  for (int j=0;j<4;j++){ int idx = base+j; if (idx < n){ rowptr[idx] = run; nxt[idx] = run; run += v[j]; } }
}

__global__ void k_scatter(const int* __restrict__ src, const int* __restrict__ dst,
                          int* __restrict__ nxt, int* __restrict__ srcs, int E){
  int e = blockIdx.x*256 + threadIdx.x;
  if (e < E){
    int pos = atomicAdd(&nxt[dst[e]], 1);
    srcs[pos] = src[e];
  }
}

// ---------------- conversions ----------------
__global__ void k_f2b(const float* __restrict__ a, unsigned short* __restrict__ b, int n4){
  int id = blockIdx.x*256 + threadIdx.x;
  if (id < n4){
    float4 v = ((const float4*)a)[id];
    ushort4 o; o.x = f2bf(v.x); o.y = f2bf(v.y); o.z = f2bf(v.z); o.w = f2bf(v.w);
    ((ushort4*)b)[id] = o;
  }
}

__global__ void k_wt(const float* __restrict__ W, unsigned short* __restrict__ Wt, int NCreal){
  int c = blockIdx.x, k = threadIdx.x, K = blockDim.x;
  float v = (c < NCreal) ? W[(size_t)k*NCreal + c] : 0.f;
  Wt[(size_t)c*K + k] = f2bf(v);
}

// ---------------- bf16 MFMA GEMM: C[M][ldc](bf16) = A[M][K](bf16) @ Bt[NB][K](bf16)^T
__global__ __launch_bounds__(256) void gemm_mfma(
    const unsigned short* __restrict__ A, const unsigned short* __restrict__ Bt,
    unsigned short* __restrict__ C, int M, int K, int ldc){
  __shared__ unsigned short sA[64][40];
  __shared__ unsigned short sB[64][40];
  const int tid = threadIdx.x;
  const int wid = tid >> 6, lane = tid & 63;
  const int r0 = blockIdx.x * 64, c0 = blockIdx.y * 64;
  const int wr = wid >> 1, wc = wid & 1;
  const int lr = tid >> 2;
  const int lk = (tid & 3) * 8;
  const int fr = lane & 15, fk = (lane >> 4) * 8;
  f32x4 acc[2][2] = {};

  for (int k0 = 0; k0 < K; k0 += 32){
    uint4 va = make_uint4(0,0,0,0);
    int row = r0 + lr;
    if (row < M) va = *(const uint4*)(A + (size_t)row*K + k0 + lk);
    *(uint4*)&sA[lr][lk] = va;
    uint4 vb = *(const uint4*)(Bt + (size_t)(c0 + lr)*K + k0 + lk);
    *(uint4*)&sB[lr][lk] = vb;
    __syncthreads();
    bf16x8 a0 = *(const bf16x8*)&sA[wr*32 + fr][fk];
    bf16x8 a1 = *(const bf16x8*)&sA[wr*32 + 16 + fr][fk];
    bf16x8 b0 = *(const bf16x8*)&sB[wc*32 + fr][fk];
    bf16x8 b1 = *(const bf16x8*)&sB[wc*32 + 16 + fr][fk];
    acc[0][0] = __builtin_amdgcn_mfma_f32_16x16x32_bf16(a0, b0, acc[0][0], 0,0,0);
    acc[0][1] = __builtin_amdgcn_mfma_f32_16x16x32_bf16(a0, b1, acc[0][1], 0,0,0);
    acc[1][0] = __builtin_amdgcn_mfma_f32_16x16x32_bf16(a1, b0, acc[1][0], 0,0,0);
    acc[1][1] = __builtin_amdgcn_mfma_f32_16x16x32_bf16(a1, b1, acc[1][1], 0,0,0);
    __syncthreads();
  }
  #pragma unroll
  for (int mi=0; mi<2; mi++){
    int rowb = r0 + wr*32 + mi*16 + (lane>>4)*4;
    #pragma unroll
    for (int ni=0; ni<2; ni++){
      int col = c0 + wc*32 + ni*16 + fr;
      #pragma unroll
      for (int j=0;j<4;j++){
        int row = rowb + j;
        if (row < M) C[(size_t)row*ldc + col] = f2bf(acc[mi][ni][j]);
      }
    }
  }
}

// ---------------- attention coefficient dots (bf16 h) ----------------
__global__ void k_att1(const unsigned short* __restrict__ h, const float* __restrict__ att_s,
    const float* __restrict__ att_d, float* __restrict__ asrc, float* __restrict__ adst, int n){
  int id = blockIdx.x*256 + threadIdx.x;   // id = node*8 + head
  if (id >= n*8) return;
  int hd = id & 7;
  const unsigned short* hv = h + (size_t)(id>>3)*256 + hd*32;
  const float* sa = att_s + hd*32;
  const float* da = att_d + hd*32;
  float s = 0.f, d = 0.f;
  #pragma unroll
  for (int q=0; q<4; q++){
    ushort4 u0 = ((const ushort4*)hv)[q*2];
    ushort4 u1 = ((const ushort4*)hv)[q*2+1];
    float v0=b2f(u0.x), v1=b2f(u0.y), v2=b2f(u0.z), v3=b2f(u0.w);
    float v4=b2f(u1.x), v5=b2f(u1.y), v6=b2f(u1.z), v7=b2f(u1.w);
    float4 a0 = ((const float4*)sa)[q*2], a1 = ((const float4*)sa)[q*2+1];
    float4 d0 = ((const float4*)da)[q*2], d1 = ((const float4*)da)[q*2+1];
    s += v0*a0.x + v1*a0.y + v2*a0.z + v3*a0.w + v4*a1.x + v5*a1.y + v6*a1.z + v7*a1.w;
    d += v0*d0.x + v1*d0.y + v2*d0.z + v3*d0.w + v4*d1.x + v5*d1.y + v6*d1.z + v7*d1.w;
  }
  asrc[id] = s; adst[id] = d;
}

__global__ void k_att2(const unsigned short* __restrict__ h, const float* __restrict__ att_s,
    const float* __restrict__ att_d, float* __restrict__ asrc, float* __restrict__ adst, int n){
  int id = blockIdx.x*256 + threadIdx.x;   // id = node
  if (id >= n) return;
  const unsigned short* hv = h + (size_t)id*64;
  float s = 0.f, d = 0.f;
  #pragma unroll
  for (int q=0; q<5; q++){
    ushort4 u0 = ((const ushort4*)hv)[q*2];
    ushort4 u1 = ((const ushort4*)hv)[q*2+1];
    float v0=b2f(u0.x), v1=b2f(u0.y), v2=b2f(u0.z), v3=b2f(u0.w);
    float v4=b2f(u1.x), v5=b2f(u1.y), v6=b2f(u1.z), v7=b2f(u1.w);
    float4 a0 = ((const float4*)att_s)[q*2], a1 = ((const float4*)att_s)[q*2+1];
    float4 d0 = ((const float4*)att_d)[q*2], d1 = ((const float4*)att_d)[q*2+1];
    s += v0*a0.x + v1*a0.y + v2*a0.z + v3*a0.w + v4*a1.x + v5*a1.y + v6*a1.z + v7*a1.w;
    d += v0*d0.x + v1*d0.y + v2*d0.z + v3*d0.w + v4*d1.x + v5*d1.y + v6*d1.z + v7*d1.w;
  }
  asrc[id] = s; adst[id] = d;
}

// ---------------- layer-1 aggregation: wave/node, bf16 gathers, online softmax, 8x unroll
__global__ __launch_bounds__(256) void k_agg1(
    const unsigned short* __restrict__ h1, const float* __restrict__ asrc,
    const float* __restrict__ adst, const int* __restrict__ rowptr,
    const int* __restrict__ srcs, const float* __restrict__ bias,
    unsigned short* __restrict__ zb, int n){
  int wid = (blockIdx.x*256 + threadIdx.x) >> 6;
  int lane = threadIdx.x & 63;
  if (wid >= n) return;
  int i = wid;
  int hd = lane >> 3;
  float adsti = adst[(size_t)i*8 + hd];
  float m = lrelu(asrc[(size_t)i*8 + hd] + adsti);   // self logit; p_self = 1
  float ssum = 1.f;
  uint2 hs = ((const uint2*)(h1 + (size_t)i*256))[lane];
  float4 acc;
  acc.x = b2f((unsigned short)(hs.x & 0xffff));
  acc.y = b2f((unsigned short)(hs.x >> 16));
  acc.z = b2f((unsigned short)(hs.y & 0xffff));
  acc.w = b2f((unsigned short)(hs.y >> 16));
  int e0 = rowptr[i], e1 = rowptr[i+1];
  int e = e0;
  for (; e + 8 <= e1; e += 8){
    int sx[8]; uint2 vv[8]; float ll[8];
    #pragma unroll
    for (int j=0;j<8;j++) sx[j] = srcs[e+j];
    #pragma unroll
    for (int j=0;j<8;j++) vv[j] = ((const uint2*)(h1 + (size_t)sx[j]*256))[lane];
    #pragma unroll
    for (int j=0;j<8;j++) ll[j] = lrelu(asrc[(size_t)sx[j]*8 + hd] + adsti);
    float gm = ll[0];
    #pragma unroll
    for (int j=1;j<8;j++) gm = fmaxf(gm, ll[j]);
    float mn = fmaxf(m, gm);
    float r = __expf(m - mn); m = mn;
    ssum *= r; acc.x *= r; acc.y *= r; acc.z *= r; acc.w *= r;
    #pragma unroll
    for (int j=0;j<8;j++){
      float p = __expf(ll[j] - m);
      ssum += p;
      acc.x += p * b2f((unsigned short)(vv[j].x & 0xffff));
      acc.y += p * b2f((unsigned short)(vv[j].x >> 16));
      acc.z += p * b2f((unsigned short)(vv[j].y & 0xffff));
      acc.w += p * b2f((unsigned short)(vv[j].y >> 16));
    }
  }
  for (; e < e1; ++e){
    int s = srcs[e];
    uint2 v = ((const uint2*)(h1 + (size_t)s*256))[lane];
    float l = lrelu(asrc[(size_t)s*8 + hd] + adsti);
    float mn = fmaxf(m, l);
    float r = __expf(m - mn);
    float p = __expf(l - mn); m = mn;
    ssum = ssum*r + p;
    acc.x = acc.x*r + p * b2f((unsigned short)(v.x & 0xffff));
    acc.y = acc.y*r + p * b2f((unsigned short)(v.x >> 16));
    acc.z = acc.z*r + p * b2f((unsigned short)(v.y & 0xffff));
    acc.w = acc.w*r + p * b2f((unsigned short)(v.y >> 16));
  }
  float inv = 1.f / ssum;
  float4 b = ((const float4*)bias)[lane];
  ushort4 ob;
  ob.x = f2bf(fmaxf(fmaf(acc.x, inv, b.x), 0.f));
  ob.y = f2bf(fmaxf(fmaf(acc.y, inv, b.y), 0.f));
  ob.z = f2bf(fmaxf(fmaf(acc.z, inv, b.z), 0.f));
  ob.w = f2bf(fmaxf(fmaf(acc.w, inv, b.w), 0.f));
  ((ushort4*)(zb + (size_t)i*256))[lane] = ob;
}

// ---------------- layer-2 aggregation + log_softmax (bf16 gathers) ----------------
__global__ __launch_bounds__(256) void k_agg2(
    const unsigned short* __restrict__ h2, const float* __restrict__ asrc,
    const float* __restrict__ adst, const int* __restrict__ rowptr,
    const int* __restrict__ srcs, const float* __restrict__ bias,
    float* __restrict__ out, int n){
  int wid = (blockIdx.x*256 + threadIdx.x) >> 6;
  int lane = threadIdx.x & 63;
  if (wid >= n) return;
  int i = wid;
  bool act = lane < 40;
  float adsti = adst[i];
  float m = lrelu(asrc[i] + adsti);
  float ssum = 1.f;
  float acc = b2f(h2[(size_t)i*64 + lane]);   // cols 40..63 are zeros
  int e0 = rowptr[i], e1 = rowptr[i+1];
  int e = e0;
  for (; e + 8 <= e1; e += 8){
    int sx[8]; float vv[8], ll[8];
    #pragma unroll
    for (int j=0;j<8;j++) sx[j] = srcs[e+j];
    #pragma unroll
    for (int j=0;j<8;j++) vv[j] = b2f(h2[(size_t)sx[j]*64 + lane]);
    #pragma unroll
    for (int j=0;j<8;j++) ll[j] = lrelu(asrc[sx[j]] + adsti);
    float gm = ll[0];
    #pragma unroll
    for (int j=1;j<8;j++) gm = fmaxf(gm, ll[j]);
    float mn = fmaxf(m, gm);
    float r = __expf(m - mn); m = mn;
    ssum *= r; acc *= r;
    #pragma unroll
    for (int j=0;j<8;j++){
      float p = __expf(ll[j] - m);
      ssum += p;
      acc += p * vv[j];
    }
  }
  for (; e < e1; ++e){
    int s = srcs[e];
    float v = b2f(h2[(size_t)s*64 + lane]);
    float l = lrelu(asrc[s] + adsti);
    float mn = fmaxf(m, l);
    float r = __expf(m - mn);
    float p = __expf(l - mn); m = mn;
    ssum = ssum*r + p;
    acc  = acc*r + p*v;
  }
  float val = act ? (acc/ssum + bias[lane]) : -INFINITY;
  float mx = val;
  #pragma unroll
  for (int off=32; off; off>>=1) mx = fmaxf(mx, __shfl_xor(mx, off));
  float ex = act ? __expf(val - mx) : 0.f;
  float se = ex;
  #pragma unroll
  for (int off=32; off; off>>=1) se += __shfl_xor(se, off);
  if (act) out[(size_t)i*40 + lane] = val - mx - __logf(se);
}

extern "C" void kernel_launch(void* const* d_in, const int* in_sizes, int n_in,
                              void* d_out, int out_size, void* d_ws, size_t ws_size,
                              hipStream_t stream){
  const float* x   = (const float*)d_in[0];
  const int*   ei  = (const int*)d_in[1];
  const float* W1  = (const float*)d_in[2];
  const float* as1 = (const float*)d_in[3];
  const float* ad1 = (const float*)d_in[4];
  const float* b1  = (const float*)d_in[5];
  const float* W2  = (const float*)d_in[6];
  const float* as2 = (const float*)d_in[7];
  const float* ad2 = (const float*)d_in[8];
  const float* b2  = (const float*)d_in[9];
  float* out = (float*)d_out;

  const int N = in_sizes[0] / 128;
  const int E = in_sizes[1] / 2;
  const int* srcI = ei;
  const int* dstI = ei + E;

  char* ws = (char*)d_ws;
  size_t off = 0;
  auto alloc = [&](size_t bytes){ void* p = ws + off; off += (bytes + 255) & ~(size_t)255; return p; };
  unsigned short* h1b = (unsigned short*)alloc((size_t)N*256*2);
  unsigned short* xb  = (unsigned short*)alloc((size_t)N*128*2);
  unsigned short* zb  = (unsigned short*)alloc((size_t)N*256*2);
  unsigned short* h2b = (unsigned short*)alloc((size_t)N*64*2);
  unsigned short* W1t = (unsigned short*)alloc((size_t)256*128*2);
  unsigned short* W2t = (unsigned short*)alloc((size_t)64*256*2);
  float* asrc1 = (float*)alloc((size_t)N*8*4);
  float* adst1 = (float*)alloc((size_t)N*8*4);
  float* asrc2 = (float*)alloc((size_t)N*4);
  float* adst2 = (float*)alloc((size_t)N*4);
  int* deg     = (int*)alloc((size_t)N*4);
  int* rowptr  = (int*)alloc((size_t)(N+1)*4);
  int* nxt     = (int*)alloc((size_t)N*4);
  int* srcs    = (int*)alloc((size_t)E*4);
  int* bsum    = (int*)alloc(256*4);
  int* boff    = (int*)alloc(256*4);
  (void)ws_size; (void)n_in; (void)out_size;

  const int nb = (N + 1023)/1024;
  hipMemsetAsync(deg, 0, (size_t)N*4, stream);
  int eb = (E + 255)/256;
  k_count <<<eb, 256, 0, stream>>>(dstI, deg, E);
  k_scan1 <<<nb, 256, 0, stream>>>(deg, bsum, N);
  k_scan2 <<<1, 64, 0, stream>>>(bsum, boff, rowptr, nb, N);
  k_scan3 <<<nb, 256, 0, stream>>>(deg, boff, rowptr, nxt, N);
  k_scatter<<<eb, 256, 0, stream>>>(srcI, dstI, nxt, srcs, E);

  // conversions
  k_f2b<<<((N*128/4) + 255)/256, 256, 0, stream>>>(x, xb, N*128/4);
  k_wt <<<256, 128, 0, stream>>>(W1, W1t, 256);
  k_wt <<<64, 256, 0, stream>>>(W2, W2t, 40);

  // layer 1
  dim3 g1((N + 63)/64, 4);
  gemm_mfma<<<g1, 256, 0, stream>>>(xb, W1t, h1b, N, 128, 256);
  k_att1<<<(N*8 + 255)/256, 256, 0, stream>>>(h1b, as1, ad1, asrc1, adst1, N);
  k_agg1<<<(N + 3)/4, 256, 0, stream>>>(h1b, asrc1, adst1, rowptr, srcs, b1, zb, N);

  // layer 2
  dim3 g2((N + 63)/64, 1);
  gemm_mfma<<<g2, 256, 0, stream>>>(zb, W2t, h2b, N, 256, 64);
  k_att2<<<(N + 255)/256, 256, 0, stream>>>(h2b, as2, ad2, asrc2, adst2, N);
  k_agg2<<<(N + 3)/4, 256, 0, stream>>>(h2b, asrc2, adst2, rowptr, srcs, b2, out, N);
}